// Round 1
// baseline (937.827 us; speedup 1.0000x reference)
//
#include <hip/hip_runtime.h>
#include <cmath>

// ---------------- small utility kernels ----------------

__global__ void transpose_kernel(const float* __restrict__ A, float* __restrict__ AT, int R, int C) {
    int i = blockIdx.x * blockDim.x + threadIdx.x;
    if (i >= R * C) return;
    int r = i / C, c = i % C;
    AT[c * R + r] = A[i];
}

__global__ void init_deg_kernel(int* __restrict__ deg, int n) {
    int i = blockIdx.x * blockDim.x + threadIdx.x;
    if (i < n) deg[i] = 1;   // self-loop
}

__global__ void hist_kernel(const int* __restrict__ dst, int* __restrict__ deg, int E) {
    int e = blockIdx.x * blockDim.x + threadIdx.x;
    if (e < E) atomicAdd(&deg[dst[e]], 1);
}

// single-block exclusive scan over deg[0..n) -> rowptr[0..n], pos copy
__global__ void scan_kernel(const int* __restrict__ deg, int* __restrict__ rowptr,
                            int* __restrict__ pos, int n) {
    const int T = 1024;
    int t = threadIdx.x;
    int per = (n + T - 1) / T;
    int beg = t * per;
    int end = min(beg + per, n);
    int sum = 0;
    for (int i = beg; i < end; i++) sum += deg[i];
    __shared__ int s[T];
    s[t] = sum;
    __syncthreads();
    for (int off = 1; off < T; off <<= 1) {
        int v = (t >= off) ? s[t - off] : 0;
        __syncthreads();
        s[t] += v;
        __syncthreads();
    }
    int running = (t > 0) ? s[t - 1] : 0;
    for (int i = beg; i < end; i++) {
        rowptr[i] = running;
        pos[i] = running;
        running += deg[i];
    }
    if (t == T - 1) rowptr[n] = s[T - 1];
}

__global__ void fill_self_kernel(int* __restrict__ pos, int* __restrict__ col, int n) {
    int i = blockIdx.x * blockDim.x + threadIdx.x;
    if (i < n) {
        int p = atomicAdd(&pos[i], 1);
        col[p] = i;
    }
}

__global__ void fill_edge_kernel(const int* __restrict__ src, const int* __restrict__ dst,
                                 int* __restrict__ pos, int* __restrict__ col, int E) {
    int e = blockIdx.x * blockDim.x + threadIdx.x;
    if (e < E) {
        int p = atomicAdd(&pos[dst[e]], 1);
        col[p] = src[e];
    }
}

// ---------------- GEMM + attention-coefficient kernel ----------------
// One thread per node. x[F] in VGPRs; WT[c][k] reads are wave-uniform -> scalar loads.
template <int F>
__global__ void gemm_att_kernel(const float* __restrict__ X, const float* __restrict__ WT,
                                const float* __restrict__ att_s, const float* __restrict__ att_d,
                                float* __restrict__ H, float* __restrict__ AS,
                                float* __restrict__ AD, int n_nodes) {
    int n = blockIdx.x * blockDim.x + threadIdx.x;
    if (n >= n_nodes) return;
    float x[F];
    const float4* xv = reinterpret_cast<const float4*>(X + (size_t)n * F);
#pragma unroll
    for (int i = 0; i < F / 4; i++) {
        float4 v = xv[i];
        x[4 * i + 0] = v.x; x[4 * i + 1] = v.y;
        x[4 * i + 2] = v.z; x[4 * i + 3] = v.w;
    }
    float* __restrict__ Hn = H + (size_t)n * 96;
#pragma unroll
    for (int h = 0; h < 4; h++) {
        float as_acc = 0.f, ad_acc = 0.f;
        for (int d = 0; d < 24; d++) {   // runtime loop; k fully unrolled
            int c = h * 24 + d;
            const float* __restrict__ w = WT + (size_t)c * F;
            float acc = 0.f;
#pragma unroll
            for (int k = 0; k < F; k++) acc = fmaf(x[k], w[k], acc);
            Hn[c] = acc;
            as_acc = fmaf(acc, att_s[h * 24 + d], as_acc);
            ad_acc = fmaf(acc, att_d[h * 24 + d], ad_acc);
        }
        AS[(size_t)n * 4 + h] = as_acc;
        AD[(size_t)n * 4 + h] = ad_acc;
    }
}

// ---------------- GAT aggregation (CSR gather, per-node block) ----------------
// block = 128 threads: (slot = t>>2, head = t&3) for edge-parallel phases;
// t<96 are channel owners for the message accumulation.
__global__ void gat_agg_kernel(const float* __restrict__ H, const float* __restrict__ AS,
                               const float* __restrict__ AD, const int* __restrict__ rowptr,
                               const int* __restrict__ col, const float* __restrict__ bias,
                               float* __restrict__ OUT) {
    int n = blockIdx.x;
    int t = threadIdx.x;
    int beg = rowptr[n];
    int deg = rowptr[n + 1] - beg;

    __shared__ float s_red[128];
    __shared__ float s_m[4];
    __shared__ float s_den[4];
    __shared__ float s_ex[32][4];
    __shared__ int s_src[32];

    int slot = t >> 2, hh = t & 3;
    float ad_n = AD[(size_t)n * 4 + hh];

    // Phase A: per-head max of leaky_relu(as[src]+ad[n])
    float mymax = -INFINITY;
    for (int i = slot; i < deg; i += 32) {
        int s = col[beg + i];
        float v = AS[(size_t)s * 4 + hh] + ad_n;
        v = v > 0.f ? v : 0.2f * v;
        mymax = fmaxf(mymax, v);
    }
    s_red[t] = mymax;
    __syncthreads();
    if (t < 4) {
        float m = -INFINITY;
        for (int i = t; i < 128; i += 4) m = fmaxf(m, s_red[i]);
        s_m[t] = m;
    }
    __syncthreads();
    float m_h = s_m[hh];

    // Phase B/C: chunked exp + channel accumulation (denominator deferred)
    float denom_part = 0.f;
    float acc = 0.f;
    int c = t;
    int head_c = t / 24;   // valid for t<96
    for (int base = 0; base < deg; base += 32) {
        int cnt = min(32, deg - base);
        if (slot < cnt) {
            int s = col[beg + base + slot];
            float v = AS[(size_t)s * 4 + hh] + ad_n;
            v = v > 0.f ? v : 0.2f * v;
            float ex = __expf(v - m_h);
            s_ex[slot][hh] = ex;
            denom_part += ex;
            if (hh == 0) s_src[slot] = s;
        }
        __syncthreads();
        if (t < 96) {
            for (int i = 0; i < cnt; i++) {
                acc = fmaf(H[(size_t)s_src[i] * 96 + c], s_ex[i][head_c], acc);
            }
        }
        __syncthreads();
    }

    // reduce denominator per head
    s_red[t] = denom_part;
    __syncthreads();
    if (t < 4) {
        float d = 0.f;
        for (int i = t; i < 128; i += 4) d += s_red[i];
        s_den[t] = d;
    }
    __syncthreads();
    if (t < 96) {
        float out = acc / (s_den[head_c] + 1e-16f) + bias[c];
        out = out > 0.f ? out : (__expf(out) - 1.f);   // ELU
        OUT[(size_t)n * 96 + c] = out;
    }
}

// ---------------- gate MLP: gate[n] = relu(h@gW1+gb1)@gw2+gb2 ----------------
__global__ void gate_kernel(const float* __restrict__ H2, const float* __restrict__ gWT1,
                            const float* __restrict__ g_b1, const float* __restrict__ g_w2,
                            const float* __restrict__ g_b2, float* __restrict__ gate, int n_nodes) {
    int n = blockIdx.x * blockDim.x + threadIdx.x;
    if (n >= n_nodes) return;
    float x[96];
    const float4* xv = reinterpret_cast<const float4*>(H2 + (size_t)n * 96);
#pragma unroll
    for (int i = 0; i < 24; i++) {
        float4 v = xv[i];
        x[4 * i + 0] = v.x; x[4 * i + 1] = v.y;
        x[4 * i + 2] = v.z; x[4 * i + 3] = v.w;
    }
    float g = g_b2[0];
    for (int j = 0; j < 48; j++) {
        const float* __restrict__ w = gWT1 + (size_t)j * 96;
        float a = g_b1[j];
#pragma unroll
        for (int k = 0; k < 96; k++) a = fmaf(x[k], w[k], a);
        a = fmaxf(a, 0.f);
        g = fmaf(a, g_w2[j], g);
    }
    gate[n] = g;
}

// ---------------- global attention pool (one block per graph) ----------------
__device__ __forceinline__ int lower_bound_dev(const int* __restrict__ arr, int n, int key) {
    int lo = 0, hi = n;
    while (lo < hi) {
        int mid = (lo + hi) >> 1;
        if (arr[mid] < key) lo = mid + 1; else hi = mid;
    }
    return lo;
}

__global__ void pool_kernel(const float* __restrict__ H2, const float* __restrict__ gate,
                            const int* __restrict__ batch, int n_nodes,
                            float* __restrict__ pooled) {
    int g = blockIdx.x, t = threadIdx.x;   // 128 threads
    __shared__ int sb, se;
    __shared__ float sred[128];
    if (t == 0) {
        sb = lower_bound_dev(batch, n_nodes, g);
        se = lower_bound_dev(batch, n_nodes, g + 1);
    }
    __syncthreads();
    int beg = sb, end = se;

    float mx = -INFINITY;
    for (int i = beg + t; i < end; i += 128) mx = fmaxf(mx, gate[i]);
    sred[t] = mx;
    __syncthreads();
    for (int off = 64; off; off >>= 1) {
        if (t < off) sred[t] = fmaxf(sred[t], sred[t + off]);
        __syncthreads();
    }
    float gm = sred[0];
    if (!isfinite(gm)) gm = 0.f;
    __syncthreads();

    float sm = 0.f;
    for (int i = beg + t; i < end; i += 128) sm += __expf(gate[i] - gm);
    sred[t] = sm;
    __syncthreads();
    for (int off = 64; off; off >>= 1) {
        if (t < off) sred[t] += sred[t + off];
        __syncthreads();
    }
    float gden = sred[0] + 1e-16f;

    if (t < 96) {
        float acc = 0.f;
        for (int i = beg; i < end; i++) {
            float w = __expf(gate[i] - gm);
            acc = fmaf(w, H2[(size_t)i * 96 + t], acc);
        }
        pooled[(size_t)g * 96 + t] = acc / gden;
    }
}

// ---------------- final MLP (one block per graph) ----------------
__global__ void final_kernel(const float* __restrict__ pooled, const float* __restrict__ f_w1,
                             const float* __restrict__ f_b1, const float* __restrict__ f_w2,
                             const float* __restrict__ f_b2, float* __restrict__ out) {
    int g = blockIdx.x, t = threadIdx.x;   // 96 threads
    __shared__ float sp[96], sh[96];
    sp[t] = pooled[(size_t)g * 96 + t];
    __syncthreads();
    float a = f_b1[t];
    for (int k = 0; k < 96; k++) a = fmaf(sp[k], f_w1[k * 96 + t], a);
    sh[t] = fmaxf(a, 0.f);
    __syncthreads();
    if (t < 3) {
        float o = f_b2[t];
        for (int k = 0; k < 96; k++) o = fmaf(sh[k], f_w2[k * 3 + t], o);
        out[g * 3 + t] = o;
    }
}

// ---------------- launch ----------------
extern "C" void kernel_launch(void* const* d_in, const int* in_sizes, int n_in,
                              void* d_out, int out_size, void* d_ws, size_t ws_size,
                              hipStream_t stream) {
    const float* x    = (const float*)d_in[0];
    const int*   ei   = (const int*)d_in[1];
    const int*   batch= (const int*)d_in[2];
    const float* W1   = (const float*)d_in[4];
    const float* as1  = (const float*)d_in[5];
    const float* ad1  = (const float*)d_in[6];
    const float* b1   = (const float*)d_in[7];
    const float* W2   = (const float*)d_in[8];
    const float* as2  = (const float*)d_in[9];
    const float* ad2  = (const float*)d_in[10];
    const float* b2   = (const float*)d_in[11];
    const float* g_w1 = (const float*)d_in[12];
    const float* g_b1 = (const float*)d_in[13];
    const float* g_w2 = (const float*)d_in[14];
    const float* g_b2 = (const float*)d_in[15];
    const float* f_w1 = (const float*)d_in[16];
    const float* f_b1 = (const float*)d_in[17];
    const float* f_w2 = (const float*)d_in[18];
    const float* f_b2 = (const float*)d_in[19];
    float* out = (float*)d_out;

    int N = in_sizes[0] / 128;
    int E = in_sizes[1] / 2;
    int G = out_size / 3;
    const int* srcv = ei;
    const int* dstv = ei + E;

    char* p = (char*)d_ws;
    auto alloc = [&](size_t bytes) {
        char* q = p;
        p += (bytes + 255) & ~(size_t)255;
        return q;
    };
    float* WT1   = (float*)alloc((size_t)128 * 96 * 4);
    float* WT2   = (float*)alloc((size_t)96 * 96 * 4);
    float* gWT1  = (float*)alloc((size_t)48 * 96 * 4);
    float* hA    = (float*)alloc((size_t)N * 96 * 4);
    float* hB    = (float*)alloc((size_t)N * 96 * 4);
    float* AS    = (float*)alloc((size_t)N * 4 * 4);
    float* AD    = (float*)alloc((size_t)N * 4 * 4);
    float* gatev = (float*)alloc((size_t)N * 4);
    float* pooled= (float*)alloc((size_t)G * 96 * 4);
    int*   deg   = (int*)alloc((size_t)N * 4);
    int*   pos   = (int*)alloc((size_t)N * 4);
    int*   rowptr= (int*)alloc(((size_t)N + 1) * 4);
    int*   col   = (int*)alloc((size_t)(E + N) * 4);

    const int B = 256;
    // weight transposes
    transpose_kernel<<<(128 * 96 + B - 1) / B, B, 0, stream>>>(W1, WT1, 128, 96);
    transpose_kernel<<<(96 * 96 + B - 1) / B, B, 0, stream>>>(W2, WT2, 96, 96);
    transpose_kernel<<<(96 * 48 + B - 1) / B, B, 0, stream>>>(g_w1, gWT1, 96, 48);

    // CSR build (by dst, self-loops included)
    init_deg_kernel<<<(N + B - 1) / B, B, 0, stream>>>(deg, N);
    hist_kernel<<<(E + B - 1) / B, B, 0, stream>>>(dstv, deg, E);
    scan_kernel<<<1, 1024, 0, stream>>>(deg, rowptr, pos, N);
    fill_self_kernel<<<(N + B - 1) / B, B, 0, stream>>>(pos, col, N);
    fill_edge_kernel<<<(E + B - 1) / B, B, 0, stream>>>(srcv, dstv, pos, col, E);

    // layer 1
    gemm_att_kernel<128><<<(N + B - 1) / B, B, 0, stream>>>(x, WT1, as1, ad1, hA, AS, AD, N);
    gat_agg_kernel<<<N, 128, 0, stream>>>(hA, AS, AD, rowptr, col, b1, hB);
    // layer 2
    gemm_att_kernel<96><<<(N + B - 1) / B, B, 0, stream>>>(hB, WT2, as2, ad2, hA, AS, AD, N);
    gat_agg_kernel<<<N, 128, 0, stream>>>(hA, AS, AD, rowptr, col, b2, hB);

    // pooling
    gate_kernel<<<(N + B - 1) / B, B, 0, stream>>>(hB, gWT1, g_b1, g_w2, g_b2, gatev, N);
    pool_kernel<<<G, 128, 0, stream>>>(hB, gatev, batch, N, pooled);
    final_kernel<<<G, 96, 0, stream>>>(pooled, f_w1, f_b1, f_w2, f_b2, out);
}

// Round 2
// 662.599 us; speedup vs baseline: 1.4154x; 1.4154x over previous
//
#include <hip/hip_runtime.h>
#include <cmath>

// ---------------- CSR build kernels ----------------

__global__ void init_deg_kernel(int* __restrict__ deg, int n) {
    int i = blockIdx.x * blockDim.x + threadIdx.x;
    if (i < n) deg[i] = 1;   // self-loop
}

__global__ void hist_kernel(const int* __restrict__ dst, int* __restrict__ deg, int E) {
    int e = blockIdx.x * blockDim.x + threadIdx.x;
    if (e < E) atomicAdd(&deg[dst[e]], 1);
}

// single-block exclusive scan over deg[0..n) -> rowptr[0..n], pos copy
__global__ void scan_kernel(const int* __restrict__ deg, int* __restrict__ rowptr,
                            int* __restrict__ pos, int n) {
    const int T = 1024;
    int t = threadIdx.x;
    int per = (n + T - 1) / T;
    int beg = t * per;
    int end = min(beg + per, n);
    int sum = 0;
    for (int i = beg; i < end; i++) sum += deg[i];
    __shared__ int s[T];
    s[t] = sum;
    __syncthreads();
    for (int off = 1; off < T; off <<= 1) {
        int v = (t >= off) ? s[t - off] : 0;
        __syncthreads();
        s[t] += v;
        __syncthreads();
    }
    int running = (t > 0) ? s[t - 1] : 0;
    for (int i = beg; i < end; i++) {
        rowptr[i] = running;
        pos[i] = running;
        running += deg[i];
    }
    if (t == T - 1) rowptr[n] = s[T - 1];
}

__global__ void fill_self_kernel(int* __restrict__ pos, int* __restrict__ col, int n) {
    int i = blockIdx.x * blockDim.x + threadIdx.x;
    if (i < n) {
        int p = atomicAdd(&pos[i], 1);
        col[p] = i;
    }
}

__global__ void fill_edge_kernel(const int* __restrict__ src, const int* __restrict__ dst,
                                 int* __restrict__ pos, int* __restrict__ col, int E) {
    int e = blockIdx.x * blockDim.x + threadIdx.x;
    if (e < E) {
        int p = atomicAdd(&pos[dst[e]], 1);
        col[p] = src[e];
    }
}

// ---------------- tiled f32 GEMM (BM=64, BK=16, 256 threads) ----------------
// MODE 0: GAT layer pre-pass. H = X@W (no bias), AS/AD = per-(node,head)
//         attention coefficients via epilogue LDS reduce.
//         v1=att_src (flat 96), v2=att_dst.  NCOL=96, TN=6.
// MODE 1: gate MLP. out H[node] = relu(X@W + g_b1) @ g_w2 + g_b2.
//         v1=g_b1, v2=g_w2, v3=g_b2.  NCOL=48, TN=3.
template<int K, int NCOL, int TN, int MODE>
__global__ __launch_bounds__(256)
void tiled_gemm_kernel(const float* __restrict__ X, const float* __restrict__ W,
                       const float* __restrict__ v1, const float* __restrict__ v2,
                       const float* __restrict__ v3,
                       float* __restrict__ H, float* __restrict__ AS, float* __restrict__ AD,
                       int n_nodes) {
    const int t = threadIdx.x;
    const int tx = t & 15, ty = t >> 4;
    const int c0 = tx * TN;       // TN consecutive output channels
    const int m0 = ty * 4;        // 4 consecutive node rows
    const int node0 = blockIdx.x * 64;

    __shared__ float As[16][68];        // [k][m], pad 64->68: 2-way bank alias (free), rows 16B-aligned
    __shared__ float Bs[16][NCOL];      // [k][c], same layout as W in memory

    float acc[4][TN];
#pragma unroll
    for (int i = 0; i < 4; i++)
#pragma unroll
        for (int j = 0; j < TN; j++) acc[i][j] = 0.f;

    const int am = t >> 2, akq = t & 3;  // A staging: node row am, float4 #akq of the 16-wide k-slab

    for (int kb = 0; kb < K; kb += 16) {
        // stage A transposed
        float4 av = make_float4(0.f, 0.f, 0.f, 0.f);
        int anode = node0 + am;
        if (anode < n_nodes)
            av = *reinterpret_cast<const float4*>(X + (size_t)anode * K + kb + akq * 4);
        As[akq * 4 + 0][am] = av.x;
        As[akq * 4 + 1][am] = av.y;
        As[akq * 4 + 2][am] = av.z;
        As[akq * 4 + 3][am] = av.w;
        // stage B: rows kb..kb+15 of W are contiguous
        {
            const float4* wsrc = reinterpret_cast<const float4*>(W + (size_t)kb * NCOL);
            float4* bdst = reinterpret_cast<float4*>(&Bs[0][0]);
            for (int i = t; i < 16 * NCOL / 4; i += 256) bdst[i] = wsrc[i];
        }
        __syncthreads();
#pragma unroll
        for (int k = 0; k < 16; k++) {
            float4 a4 = *reinterpret_cast<const float4*>(&As[k][m0]);
            float a[4] = {a4.x, a4.y, a4.z, a4.w};
            float b[TN];
            if constexpr ((TN & 1) == 0) {
#pragma unroll
                for (int j = 0; j < TN / 2; j++) {
                    float2 b2 = *reinterpret_cast<const float2*>(&Bs[k][c0 + 2 * j]);
                    b[2 * j] = b2.x; b[2 * j + 1] = b2.y;
                }
            } else {
#pragma unroll
                for (int j = 0; j < TN; j++) b[j] = Bs[k][c0 + j];
            }
#pragma unroll
            for (int i = 0; i < 4; i++)
#pragma unroll
                for (int j = 0; j < TN; j++)
                    acc[i][j] = fmaf(a[i], b[j], acc[i][j]);
        }
        __syncthreads();
    }

    if constexpr (MODE == 0) {
        __shared__ float s_as[64][16];
        __shared__ float s_ad[64][16];
#pragma unroll
        for (int i = 0; i < 4; i++) {
            int node = node0 + m0 + i;
            float asp = 0.f, adp = 0.f;
#pragma unroll
            for (int j = 0; j < TN; j++) {
                asp = fmaf(acc[i][j], v1[c0 + j], asp);
                adp = fmaf(acc[i][j], v2[c0 + j], adp);
            }
            s_as[m0 + i][tx] = asp;
            s_ad[m0 + i][tx] = adp;
            if (node < n_nodes) {
#pragma unroll
                for (int j = 0; j < TN / 2; j++) {
                    float2 o;
                    o.x = acc[i][2 * j]; o.y = acc[i][2 * j + 1];
                    *reinterpret_cast<float2*>(H + (size_t)node * NCOL + c0 + 2 * j) = o;
                }
            }
        }
        __syncthreads();
        int m = t >> 2, head = t & 3;
        int node = node0 + m;
        if (node < n_nodes) {
            float s1 = s_as[m][head * 4 + 0] + s_as[m][head * 4 + 1]
                     + s_as[m][head * 4 + 2] + s_as[m][head * 4 + 3];
            float s2 = s_ad[m][head * 4 + 0] + s_ad[m][head * 4 + 1]
                     + s_ad[m][head * 4 + 2] + s_ad[m][head * 4 + 3];
            AS[(size_t)node * 4 + head] = s1;
            AD[(size_t)node * 4 + head] = s2;
        }
    } else {
        __shared__ float s_g[64][16];
#pragma unroll
        for (int i = 0; i < 4; i++) {
            float p = 0.f;
#pragma unroll
            for (int j = 0; j < TN; j++) {
                float a = acc[i][j] + v1[c0 + j];
                a = fmaxf(a, 0.f);
                p = fmaf(a, v2[c0 + j], p);
            }
            s_g[m0 + i][tx] = p;
        }
        __syncthreads();
        if (t < 64) {
            int node = node0 + t;
            if (node < n_nodes) {
                float s = 0.f;
#pragma unroll
                for (int j = 0; j < 16; j++) s += s_g[t][j];
                H[node] = s + v3[0];
            }
        }
    }
}

// ---------------- GAT aggregation (CSR gather, per-node block) ----------------
__global__ void gat_agg_kernel(const float* __restrict__ H, const float* __restrict__ AS,
                               const float* __restrict__ AD, const int* __restrict__ rowptr,
                               const int* __restrict__ col, const float* __restrict__ bias,
                               float* __restrict__ OUT) {
    int n = blockIdx.x;
    int t = threadIdx.x;
    int beg = rowptr[n];
    int deg = rowptr[n + 1] - beg;

    __shared__ float s_red[128];
    __shared__ float s_m[4];
    __shared__ float s_den[4];
    __shared__ float s_ex[32][4];
    __shared__ int s_src[32];

    int slot = t >> 2, hh = t & 3;
    float ad_n = AD[(size_t)n * 4 + hh];

    // Phase A: per-head max of leaky_relu(as[src]+ad[n])
    float mymax = -INFINITY;
    for (int i = slot; i < deg; i += 32) {
        int s = col[beg + i];
        float v = AS[(size_t)s * 4 + hh] + ad_n;
        v = v > 0.f ? v : 0.2f * v;
        mymax = fmaxf(mymax, v);
    }
    s_red[t] = mymax;
    __syncthreads();
    if (t < 4) {
        float m = -INFINITY;
        for (int i = t; i < 128; i += 4) m = fmaxf(m, s_red[i]);
        s_m[t] = m;
    }
    __syncthreads();
    float m_h = s_m[hh];

    // Phase B/C: chunked exp + channel accumulation (denominator deferred)
    float denom_part = 0.f;
    float acc = 0.f;
    int c = t;
    int head_c = t / 24;   // valid for t<96
    for (int base = 0; base < deg; base += 32) {
        int cnt = min(32, deg - base);
        if (slot < cnt) {
            int s = col[beg + base + slot];
            float v = AS[(size_t)s * 4 + hh] + ad_n;
            v = v > 0.f ? v : 0.2f * v;
            float ex = __expf(v - m_h);
            s_ex[slot][hh] = ex;
            denom_part += ex;
            if (hh == 0) s_src[slot] = s;
        }
        __syncthreads();
        if (t < 96) {
            for (int i = 0; i < cnt; i++) {
                acc = fmaf(H[(size_t)s_src[i] * 96 + c], s_ex[i][head_c], acc);
            }
        }
        __syncthreads();
    }

    // reduce denominator per head
    s_red[t] = denom_part;
    __syncthreads();
    if (t < 4) {
        float d = 0.f;
        for (int i = t; i < 128; i += 4) d += s_red[i];
        s_den[t] = d;
    }
    __syncthreads();
    if (t < 96) {
        float out = acc / (s_den[head_c] + 1e-16f) + bias[c];
        out = out > 0.f ? out : (__expf(out) - 1.f);   // ELU
        OUT[(size_t)n * 96 + c] = out;
    }
}

// ---------------- global attention pool (one block per graph) ----------------
__device__ __forceinline__ int lower_bound_dev(const int* __restrict__ arr, int n, int key) {
    int lo = 0, hi = n;
    while (lo < hi) {
        int mid = (lo + hi) >> 1;
        if (arr[mid] < key) lo = mid + 1; else hi = mid;
    }
    return lo;
}

__global__ void pool_kernel(const float* __restrict__ H2, const float* __restrict__ gate,
                            const int* __restrict__ batch, int n_nodes,
                            float* __restrict__ pooled) {
    int g = blockIdx.x, t = threadIdx.x;   // 128 threads
    __shared__ int sb, se;
    __shared__ float sred[128];
    if (t == 0) {
        sb = lower_bound_dev(batch, n_nodes, g);
        se = lower_bound_dev(batch, n_nodes, g + 1);
    }
    __syncthreads();
    int beg = sb, end = se;

    float mx = -INFINITY;
    for (int i = beg + t; i < end; i += 128) mx = fmaxf(mx, gate[i]);
    sred[t] = mx;
    __syncthreads();
    for (int off = 64; off; off >>= 1) {
        if (t < off) sred[t] = fmaxf(sred[t], sred[t + off]);
        __syncthreads();
    }
    float gm = sred[0];
    if (!isfinite(gm)) gm = 0.f;
    __syncthreads();

    float sm = 0.f;
    for (int i = beg + t; i < end; i += 128) sm += __expf(gate[i] - gm);
    sred[t] = sm;
    __syncthreads();
    for (int off = 64; off; off >>= 1) {
        if (t < off) sred[t] += sred[t + off];
        __syncthreads();
    }
    float gden = sred[0] + 1e-16f;

    if (t < 96) {
        float acc = 0.f;
        for (int i = beg; i < end; i++) {
            float w = __expf(gate[i] - gm);
            acc = fmaf(w, H2[(size_t)i * 96 + t], acc);
        }
        pooled[(size_t)g * 96 + t] = acc / gden;
    }
}

// ---------------- final MLP (one block per graph) ----------------
__global__ void final_kernel(const float* __restrict__ pooled, const float* __restrict__ f_w1,
                             const float* __restrict__ f_b1, const float* __restrict__ f_w2,
                             const float* __restrict__ f_b2, float* __restrict__ out) {
    int g = blockIdx.x, t = threadIdx.x;   // 96 threads
    __shared__ float sp[96], sh[96];
    sp[t] = pooled[(size_t)g * 96 + t];
    __syncthreads();
    float a = f_b1[t];
    for (int k = 0; k < 96; k++) a = fmaf(sp[k], f_w1[k * 96 + t], a);
    sh[t] = fmaxf(a, 0.f);
    __syncthreads();
    if (t < 3) {
        float o = f_b2[t];
        for (int k = 0; k < 96; k++) o = fmaf(sh[k], f_w2[k * 3 + t], o);
        out[g * 3 + t] = o;
    }
}

// ---------------- launch ----------------
extern "C" void kernel_launch(void* const* d_in, const int* in_sizes, int n_in,
                              void* d_out, int out_size, void* d_ws, size_t ws_size,
                              hipStream_t stream) {
    const float* x    = (const float*)d_in[0];
    const int*   ei   = (const int*)d_in[1];
    const int*   batch= (const int*)d_in[2];
    const float* W1   = (const float*)d_in[4];
    const float* as1  = (const float*)d_in[5];
    const float* ad1  = (const float*)d_in[6];
    const float* b1   = (const float*)d_in[7];
    const float* W2   = (const float*)d_in[8];
    const float* as2  = (const float*)d_in[9];
    const float* ad2  = (const float*)d_in[10];
    const float* b2   = (const float*)d_in[11];
    const float* g_w1 = (const float*)d_in[12];
    const float* g_b1 = (const float*)d_in[13];
    const float* g_w2 = (const float*)d_in[14];
    const float* g_b2 = (const float*)d_in[15];
    const float* f_w1 = (const float*)d_in[16];
    const float* f_b1 = (const float*)d_in[17];
    const float* f_w2 = (const float*)d_in[18];
    const float* f_b2 = (const float*)d_in[19];
    float* out = (float*)d_out;

    int N = in_sizes[0] / 128;
    int E = in_sizes[1] / 2;
    int G = out_size / 3;
    const int* srcv = ei;
    const int* dstv = ei + E;

    char* p = (char*)d_ws;
    auto alloc = [&](size_t bytes) {
        char* q = p;
        p += (bytes + 255) & ~(size_t)255;
        return q;
    };
    float* hA    = (float*)alloc((size_t)N * 96 * 4);
    float* hB    = (float*)alloc((size_t)N * 96 * 4);
    float* AS    = (float*)alloc((size_t)N * 4 * 4);
    float* AD    = (float*)alloc((size_t)N * 4 * 4);
    float* gatev = (float*)alloc((size_t)N * 4);
    float* pooled= (float*)alloc((size_t)G * 96 * 4);
    int*   deg   = (int*)alloc((size_t)N * 4);
    int*   pos   = (int*)alloc((size_t)N * 4);
    int*   rowptr= (int*)alloc(((size_t)N + 1) * 4);
    int*   col   = (int*)alloc((size_t)(E + N) * 4);

    const int B = 256;
    int gemm_blocks = (N + 63) / 64;

    // CSR build (by dst, self-loops included)
    init_deg_kernel<<<(N + B - 1) / B, B, 0, stream>>>(deg, N);
    hist_kernel<<<(E + B - 1) / B, B, 0, stream>>>(dstv, deg, E);
    scan_kernel<<<1, 1024, 0, stream>>>(deg, rowptr, pos, N);
    fill_self_kernel<<<(N + B - 1) / B, B, 0, stream>>>(pos, col, N);
    fill_edge_kernel<<<(E + B - 1) / B, B, 0, stream>>>(srcv, dstv, pos, col, E);

    // layer 1
    tiled_gemm_kernel<128, 96, 6, 0><<<gemm_blocks, 256, 0, stream>>>(
        x, W1, as1, ad1, nullptr, hA, AS, AD, N);
    gat_agg_kernel<<<N, 128, 0, stream>>>(hA, AS, AD, rowptr, col, b1, hB);
    // layer 2
    tiled_gemm_kernel<96, 96, 6, 0><<<gemm_blocks, 256, 0, stream>>>(
        hB, W2, as2, ad2, nullptr, hA, AS, AD, N);
    gat_agg_kernel<<<N, 128, 0, stream>>>(hA, AS, AD, rowptr, col, b2, hB);

    // pooling
    tiled_gemm_kernel<96, 48, 3, 1><<<gemm_blocks, 256, 0, stream>>>(
        hB, g_w1, g_b1, g_w2, g_b2, gatev, nullptr, nullptr, N);
    pool_kernel<<<G, 128, 0, stream>>>(hB, gatev, batch, N, pooled);
    final_kernel<<<G, 96, 0, stream>>>(pooled, f_w1, f_b1, f_w2, f_b2, out);
}

// Round 3
// 496.584 us; speedup vs baseline: 1.8886x; 1.3343x over previous
//
#include <hip/hip_runtime.h>
#include <cmath>

// ---------------- CSR build kernels ----------------

__global__ void init_deg_kernel(int* __restrict__ deg, int n) {
    int i = blockIdx.x * blockDim.x + threadIdx.x;
    if (i < n) deg[i] = 1;   // self-loop
}

__global__ void hist_kernel(const int* __restrict__ dst, int* __restrict__ deg, int E) {
    int e = blockIdx.x * blockDim.x + threadIdx.x;
    if (e < E) atomicAdd(&deg[dst[e]], 1);
}

// single-block exclusive scan over deg[0..n) -> rowptr[0..n], pos copy
__global__ void scan_kernel(const int* __restrict__ deg, int* __restrict__ rowptr,
                            int* __restrict__ pos, int n) {
    const int T = 1024;
    int t = threadIdx.x;
    int per = (n + T - 1) / T;
    int beg = t * per;
    int end = min(beg + per, n);
    int sum = 0;
    for (int i = beg; i < end; i++) sum += deg[i];
    __shared__ int s[T];
    s[t] = sum;
    __syncthreads();
    for (int off = 1; off < T; off <<= 1) {
        int v = (t >= off) ? s[t - off] : 0;
        __syncthreads();
        s[t] += v;
        __syncthreads();
    }
    int running = (t > 0) ? s[t - 1] : 0;
    for (int i = beg; i < end; i++) {
        rowptr[i] = running;
        pos[i] = running;
        running += deg[i];
    }
    if (t == T - 1) rowptr[n] = s[T - 1];
}

__global__ void fill_self_kernel(int* __restrict__ pos, int* __restrict__ col, int n) {
    int i = blockIdx.x * blockDim.x + threadIdx.x;
    if (i < n) {
        int p = atomicAdd(&pos[i], 1);
        col[p] = i;
    }
}

__global__ void fill_edge_kernel(const int* __restrict__ src, const int* __restrict__ dst,
                                 int* __restrict__ pos, int* __restrict__ col, int E) {
    int e = blockIdx.x * blockDim.x + threadIdx.x;
    if (e < E) {
        int p = atomicAdd(&pos[dst[e]], 1);
        col[p] = src[e];
    }
}

// ---------------- tiled f32 GEMM (BM=64, BK=16, 256 threads) ----------------
// MODE 0: GAT layer pre-pass. H = X@W (no bias), AS/AD via epilogue LDS reduce.
// MODE 1: gate MLP. H[node] = relu(X@W + g_b1) @ g_w2 + g_b2.
template<int K, int NCOL, int TN, int MODE>
__global__ __launch_bounds__(256)
void tiled_gemm_kernel(const float* __restrict__ X, const float* __restrict__ W,
                       const float* __restrict__ v1, const float* __restrict__ v2,
                       const float* __restrict__ v3,
                       float* __restrict__ H, float* __restrict__ AS, float* __restrict__ AD,
                       int n_nodes) {
    const int t = threadIdx.x;
    const int tx = t & 15, ty = t >> 4;
    const int c0 = tx * TN;
    const int m0 = ty * 4;
    const int node0 = blockIdx.x * 64;

    __shared__ float As[16][68];
    __shared__ float Bs[16][NCOL];

    float acc[4][TN];
#pragma unroll
    for (int i = 0; i < 4; i++)
#pragma unroll
        for (int j = 0; j < TN; j++) acc[i][j] = 0.f;

    const int am = t >> 2, akq = t & 3;

    for (int kb = 0; kb < K; kb += 16) {
        float4 av = make_float4(0.f, 0.f, 0.f, 0.f);
        int anode = node0 + am;
        if (anode < n_nodes)
            av = *reinterpret_cast<const float4*>(X + (size_t)anode * K + kb + akq * 4);
        As[akq * 4 + 0][am] = av.x;
        As[akq * 4 + 1][am] = av.y;
        As[akq * 4 + 2][am] = av.z;
        As[akq * 4 + 3][am] = av.w;
        {
            const float4* wsrc = reinterpret_cast<const float4*>(W + (size_t)kb * NCOL);
            float4* bdst = reinterpret_cast<float4*>(&Bs[0][0]);
            for (int i = t; i < 16 * NCOL / 4; i += 256) bdst[i] = wsrc[i];
        }
        __syncthreads();
#pragma unroll
        for (int k = 0; k < 16; k++) {
            float4 a4 = *reinterpret_cast<const float4*>(&As[k][m0]);
            float a[4] = {a4.x, a4.y, a4.z, a4.w};
            float b[TN];
            if constexpr ((TN & 1) == 0) {
#pragma unroll
                for (int j = 0; j < TN / 2; j++) {
                    float2 b2 = *reinterpret_cast<const float2*>(&Bs[k][c0 + 2 * j]);
                    b[2 * j] = b2.x; b[2 * j + 1] = b2.y;
                }
            } else {
#pragma unroll
                for (int j = 0; j < TN; j++) b[j] = Bs[k][c0 + j];
            }
#pragma unroll
            for (int i = 0; i < 4; i++)
#pragma unroll
                for (int j = 0; j < TN; j++)
                    acc[i][j] = fmaf(a[i], b[j], acc[i][j]);
        }
        __syncthreads();
    }

    if constexpr (MODE == 0) {
        __shared__ float s_as[64][16];
        __shared__ float s_ad[64][16];
#pragma unroll
        for (int i = 0; i < 4; i++) {
            int node = node0 + m0 + i;
            float asp = 0.f, adp = 0.f;
#pragma unroll
            for (int j = 0; j < TN; j++) {
                asp = fmaf(acc[i][j], v1[c0 + j], asp);
                adp = fmaf(acc[i][j], v2[c0 + j], adp);
            }
            s_as[m0 + i][tx] = asp;
            s_ad[m0 + i][tx] = adp;
            if (node < n_nodes) {
#pragma unroll
                for (int j = 0; j < TN / 2; j++) {
                    float2 o;
                    o.x = acc[i][2 * j]; o.y = acc[i][2 * j + 1];
                    *reinterpret_cast<float2*>(H + (size_t)node * NCOL + c0 + 2 * j) = o;
                }
            }
        }
        __syncthreads();
        int m = t >> 2, head = t & 3;
        int node = node0 + m;
        if (node < n_nodes) {
            float s1 = s_as[m][head * 4 + 0] + s_as[m][head * 4 + 1]
                     + s_as[m][head * 4 + 2] + s_as[m][head * 4 + 3];
            float s2 = s_ad[m][head * 4 + 0] + s_ad[m][head * 4 + 1]
                     + s_ad[m][head * 4 + 2] + s_ad[m][head * 4 + 3];
            AS[(size_t)node * 4 + head] = s1;
            AD[(size_t)node * 4 + head] = s2;
        }
    } else {
        __shared__ float s_g[64][16];
#pragma unroll
        for (int i = 0; i < 4; i++) {
            float p = 0.f;
#pragma unroll
            for (int j = 0; j < TN; j++) {
                float a = acc[i][j] + v1[c0 + j];
                a = fmaxf(a, 0.f);
                p = fmaf(a, v2[c0 + j], p);
            }
            s_g[m0 + i][tx] = p;
        }
        __syncthreads();
        if (t < 64) {
            int node = node0 + t;
            if (node < n_nodes) {
                float s = 0.f;
#pragma unroll
                for (int j = 0; j < 16; j++) s += s_g[t][j];
                H[node] = s + v3[0];
            }
        }
    }
}

// ---------------- GAT aggregation (CSR gather, per-node block) ----------------
__global__ void gat_agg_kernel(const float* __restrict__ H, const float* __restrict__ AS,
                               const float* __restrict__ AD, const int* __restrict__ rowptr,
                               const int* __restrict__ col, const float* __restrict__ bias,
                               float* __restrict__ OUT) {
    int n = blockIdx.x;
    int t = threadIdx.x;
    int beg = rowptr[n];
    int deg = rowptr[n + 1] - beg;

    __shared__ float s_red[128];
    __shared__ float s_m[4];
    __shared__ float s_den[4];
    __shared__ float s_ex[32][4];
    __shared__ int s_src[32];

    int slot = t >> 2, hh = t & 3;
    float ad_n = AD[(size_t)n * 4 + hh];

    float mymax = -INFINITY;
    for (int i = slot; i < deg; i += 32) {
        int s = col[beg + i];
        float v = AS[(size_t)s * 4 + hh] + ad_n;
        v = v > 0.f ? v : 0.2f * v;
        mymax = fmaxf(mymax, v);
    }
    s_red[t] = mymax;
    __syncthreads();
    if (t < 4) {
        float m = -INFINITY;
        for (int i = t; i < 128; i += 4) m = fmaxf(m, s_red[i]);
        s_m[t] = m;
    }
    __syncthreads();
    float m_h = s_m[hh];

    float denom_part = 0.f;
    float acc = 0.f;
    int c = t;
    int head_c = t / 24;
    for (int base = 0; base < deg; base += 32) {
        int cnt = min(32, deg - base);
        if (slot < cnt) {
            int s = col[beg + base + slot];
            float v = AS[(size_t)s * 4 + hh] + ad_n;
            v = v > 0.f ? v : 0.2f * v;
            float ex = __expf(v - m_h);
            s_ex[slot][hh] = ex;
            denom_part += ex;
            if (hh == 0) s_src[slot] = s;
        }
        __syncthreads();
        if (t < 96) {
            for (int i = 0; i < cnt; i++) {
                acc = fmaf(H[(size_t)s_src[i] * 96 + c], s_ex[i][head_c], acc);
            }
        }
        __syncthreads();
    }

    s_red[t] = denom_part;
    __syncthreads();
    if (t < 4) {
        float d = 0.f;
        for (int i = t; i < 128; i += 4) d += s_red[i];
        s_den[t] = d;
    }
    __syncthreads();
    if (t < 96) {
        float out = acc / (s_den[head_c] + 1e-16f) + bias[c];
        out = out > 0.f ? out : (__expf(out) - 1.f);   // ELU
        OUT[(size_t)n * 96 + c] = out;
    }
}

// ---------------- pooling, stage 1: per-graph softmax stats ----------------
__device__ __forceinline__ int lower_bound_dev(const int* __restrict__ arr, int n, int key) {
    int lo = 0, hi = n;
    while (lo < hi) {
        int mid = (lo + hi) >> 1;
        if (arr[mid] < key) lo = mid + 1; else hi = mid;
    }
    return lo;
}

__global__ void gate_stats_kernel(const float* __restrict__ gate, const int* __restrict__ batch,
                                  int n_nodes, float* __restrict__ gm_out,
                                  float* __restrict__ inv_gden_out) {
    int g = blockIdx.x, t = threadIdx.x;   // 256 threads
    __shared__ int sb, se;
    __shared__ float sred[256];
    if (t == 0) {
        sb = lower_bound_dev(batch, n_nodes, g);
        se = lower_bound_dev(batch, n_nodes, g + 1);
    }
    __syncthreads();
    int beg = sb, end = se;

    float mx = -INFINITY;
    for (int i = beg + t; i < end; i += 256) mx = fmaxf(mx, gate[i]);
    sred[t] = mx;
    __syncthreads();
    for (int off = 128; off; off >>= 1) {
        if (t < off) sred[t] = fmaxf(sred[t], sred[t + off]);
        __syncthreads();
    }
    float gm = sred[0];
    if (!isfinite(gm)) gm = 0.f;
    __syncthreads();

    float sm = 0.f;
    for (int i = beg + t; i < end; i += 256) sm += __expf(gate[i] - gm);
    sred[t] = sm;
    __syncthreads();
    for (int off = 128; off; off >>= 1) {
        if (t < off) sred[t] += sred[t + off];
        __syncthreads();
    }
    if (t == 0) {
        gm_out[g] = gm;
        inv_gden_out[g] = 1.f / (sred[0] + 1e-16f);
    }
}

__global__ void zero_kernel(float* __restrict__ p, int n) {
    int i = blockIdx.x * blockDim.x + threadIdx.x;
    if (i < n) p[i] = 0.f;
}

// ---------------- pooling, stage 2: weighted segment-sum over nodes ----------------
// 384 threads = 4 groups x 96 channels; each group walks nodes strided by 4.
__global__ __launch_bounds__(384)
void pool_accum_kernel(const float* __restrict__ H2, const float* __restrict__ gate,
                       const int* __restrict__ batch, const float* __restrict__ gm,
                       const float* __restrict__ inv_gden, int n_nodes,
                       float* __restrict__ pooled) {
    const int NPB = 256;
    int t = threadIdx.x;
    int group = t / 96;      // 0..3
    int c = t - group * 96;  // channel
    if (group >= 4) return;
    int nbeg = blockIdx.x * NPB;
    int nend = min(nbeg + NPB, n_nodes);

    float acc = 0.f;
    int curg = -1;
    for (int i = nbeg + group; i < nend; i += 4) {
        int g = batch[i];
        if (g != curg) {
            if (curg >= 0) atomicAdd(&pooled[(size_t)curg * 96 + c], acc);
            acc = 0.f;
            curg = g;
        }
        float w = __expf(gate[i] - gm[curg]) * inv_gden[curg];
        acc = fmaf(w, H2[(size_t)i * 96 + c], acc);
    }
    if (curg >= 0) atomicAdd(&pooled[(size_t)curg * 96 + c], acc);
}

// ---------------- final MLP (one block per graph) ----------------
__global__ void final_kernel(const float* __restrict__ pooled, const float* __restrict__ f_w1,
                             const float* __restrict__ f_b1, const float* __restrict__ f_w2,
                             const float* __restrict__ f_b2, float* __restrict__ out) {
    int g = blockIdx.x, t = threadIdx.x;   // 96 threads
    __shared__ float sp[96], sh[96];
    sp[t] = pooled[(size_t)g * 96 + t];
    __syncthreads();
    float a = f_b1[t];
    for (int k = 0; k < 96; k++) a = fmaf(sp[k], f_w1[k * 96 + t], a);
    sh[t] = fmaxf(a, 0.f);
    __syncthreads();
    if (t < 3) {
        float o = f_b2[t];
        for (int k = 0; k < 96; k++) o = fmaf(sh[k], f_w2[k * 3 + t], o);
        out[g * 3 + t] = o;
    }
}

// ---------------- launch ----------------
extern "C" void kernel_launch(void* const* d_in, const int* in_sizes, int n_in,
                              void* d_out, int out_size, void* d_ws, size_t ws_size,
                              hipStream_t stream) {
    const float* x    = (const float*)d_in[0];
    const int*   ei   = (const int*)d_in[1];
    const int*   batch= (const int*)d_in[2];
    const float* W1   = (const float*)d_in[4];
    const float* as1  = (const float*)d_in[5];
    const float* ad1  = (const float*)d_in[6];
    const float* b1   = (const float*)d_in[7];
    const float* W2   = (const float*)d_in[8];
    const float* as2  = (const float*)d_in[9];
    const float* ad2  = (const float*)d_in[10];
    const float* b2   = (const float*)d_in[11];
    const float* g_w1 = (const float*)d_in[12];
    const float* g_b1 = (const float*)d_in[13];
    const float* g_w2 = (const float*)d_in[14];
    const float* g_b2 = (const float*)d_in[15];
    const float* f_w1 = (const float*)d_in[16];
    const float* f_b1 = (const float*)d_in[17];
    const float* f_w2 = (const float*)d_in[18];
    const float* f_b2 = (const float*)d_in[19];
    float* out = (float*)d_out;

    int N = in_sizes[0] / 128;
    int E = in_sizes[1] / 2;
    int G = out_size / 3;
    const int* srcv = ei;
    const int* dstv = ei + E;

    char* p = (char*)d_ws;
    auto alloc = [&](size_t bytes) {
        char* q = p;
        p += (bytes + 255) & ~(size_t)255;
        return q;
    };
    float* hA    = (float*)alloc((size_t)N * 96 * 4);
    float* hB    = (float*)alloc((size_t)N * 96 * 4);
    float* AS    = (float*)alloc((size_t)N * 4 * 4);
    float* AD    = (float*)alloc((size_t)N * 4 * 4);
    float* gatev = (float*)alloc((size_t)N * 4);
    float* pooled= (float*)alloc((size_t)G * 96 * 4);
    float* gmv   = (float*)alloc((size_t)G * 4);
    float* invgd = (float*)alloc((size_t)G * 4);
    int*   deg   = (int*)alloc((size_t)N * 4);
    int*   pos   = (int*)alloc((size_t)N * 4);
    int*   rowptr= (int*)alloc(((size_t)N + 1) * 4);
    int*   col   = (int*)alloc((size_t)(E + N) * 4);

    const int B = 256;
    int gemm_blocks = (N + 63) / 64;

    // CSR build (by dst, self-loops included)
    init_deg_kernel<<<(N + B - 1) / B, B, 0, stream>>>(deg, N);
    hist_kernel<<<(E + B - 1) / B, B, 0, stream>>>(dstv, deg, E);
    scan_kernel<<<1, 1024, 0, stream>>>(deg, rowptr, pos, N);
    fill_self_kernel<<<(N + B - 1) / B, B, 0, stream>>>(pos, col, N);
    fill_edge_kernel<<<(E + B - 1) / B, B, 0, stream>>>(srcv, dstv, pos, col, E);

    // layer 1
    tiled_gemm_kernel<128, 96, 6, 0><<<gemm_blocks, 256, 0, stream>>>(
        x, W1, as1, ad1, nullptr, hA, AS, AD, N);
    gat_agg_kernel<<<N, 128, 0, stream>>>(hA, AS, AD, rowptr, col, b1, hB);
    // layer 2
    tiled_gemm_kernel<96, 96, 6, 0><<<gemm_blocks, 256, 0, stream>>>(
        hB, W2, as2, ad2, nullptr, hA, AS, AD, N);
    gat_agg_kernel<<<N, 128, 0, stream>>>(hA, AS, AD, rowptr, col, b2, hB);

    // pooling
    tiled_gemm_kernel<96, 48, 3, 1><<<gemm_blocks, 256, 0, stream>>>(
        hB, g_w1, g_b1, g_w2, g_b2, gatev, nullptr, nullptr, N);
    gate_stats_kernel<<<G, 256, 0, stream>>>(gatev, batch, N, gmv, invgd);
    zero_kernel<<<(G * 96 + B - 1) / B, B, 0, stream>>>(pooled, G * 96);
    pool_accum_kernel<<<(N + 255) / 256, 384, 0, stream>>>(
        hB, gatev, batch, gmv, invgd, N, pooled);
    final_kernel<<<G, 96, 0, stream>>>(pooled, f_w1, f_b1, f_w2, f_b2, out);
}

// Round 4
// 359.592 us; speedup vs baseline: 2.6080x; 1.3810x over previous
//
#include <hip/hip_runtime.h>
#include <cmath>

// ---------------- CSR build kernels ----------------

__global__ void init_deg_kernel(int* __restrict__ deg, int n) {
    int i = blockIdx.x * blockDim.x + threadIdx.x;
    if (i < n) deg[i] = 1;   // self-loop
}

__global__ void hist_kernel(const int* __restrict__ dst, int* __restrict__ deg, int E) {
    int e = blockIdx.x * blockDim.x + threadIdx.x;
    if (e < E) atomicAdd(&deg[dst[e]], 1);
}

// ---- hierarchical exclusive scan: deg[0..n) -> rowptr[0..n], pos copy ----
// phase 1: per-block (1024 elems) sums
__global__ void scan_bsum_kernel(const int* __restrict__ deg, int* __restrict__ bsum, int n) {
    __shared__ int s[256];
    int t = threadIdx.x;
    int base = blockIdx.x * 1024;
    int sum = 0;
#pragma unroll
    for (int j = 0; j < 4; j++) {
        int i = base + j * 256 + t;
        if (i < n) sum += deg[i];
    }
    s[t] = sum;
    __syncthreads();
    for (int off = 128; off; off >>= 1) {
        if (t < off) s[t] += s[t + off];
        __syncthreads();
    }
    if (t == 0) bsum[blockIdx.x] = s[0];
}

// phase 2: single-block exclusive scan of bsum (nb <= 256); writes rowptr[n]=total
__global__ void scan_bsum_scan_kernel(int* __restrict__ bsum, int nb,
                                      int* __restrict__ rowptr, int n) {
    __shared__ int s[256];
    int t = threadIdx.x;
    int v = (t < nb) ? bsum[t] : 0;
    s[t] = v;
    __syncthreads();
    for (int off = 1; off < 256; off <<= 1) {
        int x = (t >= off) ? s[t - off] : 0;
        __syncthreads();
        s[t] += x;
        __syncthreads();
    }
    if (t < nb) bsum[t] = s[t] - v;   // exclusive
    if (t == 255) rowptr[n] = s[255];
}

// phase 3: per-block local scan + block offset
__global__ void scan_local_kernel(const int* __restrict__ deg, const int* __restrict__ bsum,
                                  int* __restrict__ rowptr, int* __restrict__ pos, int n) {
    __shared__ int s[256];
    int t = threadIdx.x;
    int base = blockIdx.x * 1024;
    int d[4];
    int sum = 0;
#pragma unroll
    for (int j = 0; j < 4; j++) {
        int i = base + t * 4 + j;
        d[j] = (i < n) ? deg[i] : 0;
        sum += d[j];
    }
    s[t] = sum;
    __syncthreads();
    for (int off = 1; off < 256; off <<= 1) {
        int x = (t >= off) ? s[t - off] : 0;
        __syncthreads();
        s[t] += x;
        __syncthreads();
    }
    int run = bsum[blockIdx.x] + s[t] - sum;
#pragma unroll
    for (int j = 0; j < 4; j++) {
        int i = base + t * 4 + j;
        if (i < n) { rowptr[i] = run; pos[i] = run; }
        run += d[j];
    }
}

__global__ void fill_self_kernel(int* __restrict__ pos, int* __restrict__ col, int n) {
    int i = blockIdx.x * blockDim.x + threadIdx.x;
    if (i < n) {
        int p = atomicAdd(&pos[i], 1);
        col[p] = i;
    }
}

__global__ void fill_edge_kernel(const int* __restrict__ src, const int* __restrict__ dst,
                                 int* __restrict__ pos, int* __restrict__ col, int E) {
    int e = blockIdx.x * blockDim.x + threadIdx.x;
    if (e < E) {
        int p = atomicAdd(&pos[dst[e]], 1);
        col[p] = src[e];
    }
}

// ---------------- tiled f32 GEMM (BM=64, BK=16, 256 threads) ----------------
// MODE 0: GAT layer pre-pass. H = X@W (no bias), AS/AD via epilogue LDS reduce.
// MODE 1: gate MLP. H[node] = relu(X@W + g_b1) @ g_w2 + g_b2.
template<int K, int NCOL, int TN, int MODE>
__global__ __launch_bounds__(256)
void tiled_gemm_kernel(const float* __restrict__ X, const float* __restrict__ W,
                       const float* __restrict__ v1, const float* __restrict__ v2,
                       const float* __restrict__ v3,
                       float* __restrict__ H, float* __restrict__ AS, float* __restrict__ AD,
                       int n_nodes) {
    const int t = threadIdx.x;
    const int tx = t & 15, ty = t >> 4;
    const int c0 = tx * TN;
    const int m0 = ty * 4;
    const int node0 = blockIdx.x * 64;

    __shared__ float As[16][68];
    __shared__ float Bs[16][NCOL];

    float acc[4][TN];
#pragma unroll
    for (int i = 0; i < 4; i++)
#pragma unroll
        for (int j = 0; j < TN; j++) acc[i][j] = 0.f;

    const int am = t >> 2, akq = t & 3;

    for (int kb = 0; kb < K; kb += 16) {
        float4 av = make_float4(0.f, 0.f, 0.f, 0.f);
        int anode = node0 + am;
        if (anode < n_nodes)
            av = *reinterpret_cast<const float4*>(X + (size_t)anode * K + kb + akq * 4);
        As[akq * 4 + 0][am] = av.x;
        As[akq * 4 + 1][am] = av.y;
        As[akq * 4 + 2][am] = av.z;
        As[akq * 4 + 3][am] = av.w;
        {
            const float4* wsrc = reinterpret_cast<const float4*>(W + (size_t)kb * NCOL);
            float4* bdst = reinterpret_cast<float4*>(&Bs[0][0]);
            for (int i = t; i < 16 * NCOL / 4; i += 256) bdst[i] = wsrc[i];
        }
        __syncthreads();
#pragma unroll
        for (int k = 0; k < 16; k++) {
            float4 a4 = *reinterpret_cast<const float4*>(&As[k][m0]);
            float a[4] = {a4.x, a4.y, a4.z, a4.w};
            float b[TN];
            if constexpr ((TN & 1) == 0) {
#pragma unroll
                for (int j = 0; j < TN / 2; j++) {
                    float2 b2 = *reinterpret_cast<const float2*>(&Bs[k][c0 + 2 * j]);
                    b[2 * j] = b2.x; b[2 * j + 1] = b2.y;
                }
            } else {
#pragma unroll
                for (int j = 0; j < TN; j++) b[j] = Bs[k][c0 + j];
            }
#pragma unroll
            for (int i = 0; i < 4; i++)
#pragma unroll
                for (int j = 0; j < TN; j++)
                    acc[i][j] = fmaf(a[i], b[j], acc[i][j]);
        }
        __syncthreads();
    }

    if constexpr (MODE == 0) {
        __shared__ float s_as[64][16];
        __shared__ float s_ad[64][16];
#pragma unroll
        for (int i = 0; i < 4; i++) {
            int node = node0 + m0 + i;
            float asp = 0.f, adp = 0.f;
#pragma unroll
            for (int j = 0; j < TN; j++) {
                asp = fmaf(acc[i][j], v1[c0 + j], asp);
                adp = fmaf(acc[i][j], v2[c0 + j], adp);
            }
            s_as[m0 + i][tx] = asp;
            s_ad[m0 + i][tx] = adp;
            if (node < n_nodes) {
#pragma unroll
                for (int j = 0; j < TN / 2; j++) {
                    float2 o;
                    o.x = acc[i][2 * j]; o.y = acc[i][2 * j + 1];
                    *reinterpret_cast<float2*>(H + (size_t)node * NCOL + c0 + 2 * j) = o;
                }
            }
        }
        __syncthreads();
        int m = t >> 2, head = t & 3;
        int node = node0 + m;
        if (node < n_nodes) {
            float s1 = s_as[m][head * 4 + 0] + s_as[m][head * 4 + 1]
                     + s_as[m][head * 4 + 2] + s_as[m][head * 4 + 3];
            float s2 = s_ad[m][head * 4 + 0] + s_ad[m][head * 4 + 1]
                     + s_ad[m][head * 4 + 2] + s_ad[m][head * 4 + 3];
            AS[(size_t)node * 4 + head] = s1;
            AD[(size_t)node * 4 + head] = s2;
        }
    } else {
        __shared__ float s_g[64][16];
#pragma unroll
        for (int i = 0; i < 4; i++) {
            float p = 0.f;
#pragma unroll
            for (int j = 0; j < TN; j++) {
                float a = acc[i][j] + v1[c0 + j];
                a = fmaxf(a, 0.f);
                p = fmaf(a, v2[c0 + j], p);
            }
            s_g[m0 + i][tx] = p;
        }
        __syncthreads();
        if (t < 64) {
            int node = node0 + t;
            if (node < n_nodes) {
                float s = 0.f;
#pragma unroll
                for (int j = 0; j < 16; j++) s += s_g[t][j];
                H[node] = s + v3[0];
            }
        }
    }
}

// ---------------- GAT aggregation: wave-synchronous, 1 wave per node ----------------
// 256 threads = 4 waves = 4 nodes. No LDS, no barriers.
// lane layout: (slot = lane>>2, head = lane&3) for edge phases;
// lanes 0..47 own float2 channel pairs (2c, 2c+1) for accumulation.
__global__ __launch_bounds__(256)
void gat_agg_wave_kernel(const float* __restrict__ H, const float* __restrict__ AS,
                         const float* __restrict__ AD, const int* __restrict__ rowptr,
                         const int* __restrict__ col, const float* __restrict__ bias,
                         float* __restrict__ OUT, int n_nodes) {
    int wid = threadIdx.x >> 6;
    int lane = threadIdx.x & 63;
    int n = blockIdx.x * 4 + wid;
    if (n >= n_nodes) return;   // wave-uniform exit
    int beg = rowptr[n];
    int deg = rowptr[n + 1] - beg;

    int h = lane & 3;
    int slot = lane >> 2;
    float ad_n = AD[(size_t)n * 4 + h];

    // Phase A: per-head max of leaky_relu(as[src]+ad[n])
    float mymax = -INFINITY;
    for (int i = slot; i < deg; i += 16) {
        int s = col[beg + i];
        float v = AS[(size_t)s * 4 + h] + ad_n;
        v = v > 0.f ? v : 0.2f * v;
        mymax = fmaxf(mymax, v);
    }
#pragma unroll
    for (int m = 4; m <= 32; m <<= 1)
        mymax = fmaxf(mymax, __shfl_xor(mymax, m, 64));
    float m_h = mymax;   // all lanes of head h now hold that head's max

    int c = lane;                       // float2 channel-pair index
    bool cown = c < 48;
    int head_c = cown ? (c / 12) : 0;   // head of channels (2c,2c+1)
    const float2* H2v = reinterpret_cast<const float2*>(H);

    float denom_part = 0.f;
    float2 acc = make_float2(0.f, 0.f);

    for (int base = 0; base < deg; base += 16) {
        int ce = base + slot;
        int s_e = 0;
        float ex = 0.f;
        if (ce < deg) {
            s_e = col[beg + ce];
            float v = AS[(size_t)s_e * 4 + h] + ad_n;
            v = v > 0.f ? v : 0.2f * v;
            ex = __expf(v - m_h);
        }
        denom_part += ex;
        int cnt = min(16, deg - base);
        for (int i = 0; i < cnt; i++) {
            int sb = __shfl(s_e, i * 4, 64);
            float w = __shfl(ex, i * 4 + head_c, 64);
            if (cown) {
                float2 hv = H2v[(size_t)sb * 48 + c];
                acc.x = fmaf(hv.x, w, acc.x);
                acc.y = fmaf(hv.y, w, acc.y);
            }
        }
    }

#pragma unroll
    for (int m = 4; m <= 32; m <<= 1)
        denom_part += __shfl_xor(denom_part, m, 64);
    float den = __shfl(denom_part, head_c, 64);   // lane head_c holds head_c's denom

    if (cown) {
        float2 b2 = reinterpret_cast<const float2*>(bias)[c];
        float inv = 1.f / (den + 1e-16f);
        float ox = acc.x * inv + b2.x;
        float oy = acc.y * inv + b2.y;
        ox = ox > 0.f ? ox : (__expf(ox) - 1.f);   // ELU
        oy = oy > 0.f ? oy : (__expf(oy) - 1.f);
        reinterpret_cast<float2*>(OUT)[(size_t)n * 48 + c] = make_float2(ox, oy);
    }
}

// ---------------- pooling, stage 1: per-graph softmax stats ----------------
__device__ __forceinline__ int lower_bound_dev(const int* __restrict__ arr, int n, int key) {
    int lo = 0, hi = n;
    while (lo < hi) {
        int mid = (lo + hi) >> 1;
        if (arr[mid] < key) lo = mid + 1; else hi = mid;
    }
    return lo;
}

__global__ void gate_stats_kernel(const float* __restrict__ gate, const int* __restrict__ batch,
                                  int n_nodes, float* __restrict__ gm_out,
                                  float* __restrict__ inv_gden_out) {
    int g = blockIdx.x, t = threadIdx.x;   // 256 threads
    __shared__ int sb, se;
    __shared__ float sred[256];
    if (t == 0) {
        sb = lower_bound_dev(batch, n_nodes, g);
        se = lower_bound_dev(batch, n_nodes, g + 1);
    }
    __syncthreads();
    int beg = sb, end = se;

    float mx = -INFINITY;
    for (int i = beg + t; i < end; i += 256) mx = fmaxf(mx, gate[i]);
    sred[t] = mx;
    __syncthreads();
    for (int off = 128; off; off >>= 1) {
        if (t < off) sred[t] = fmaxf(sred[t], sred[t + off]);
        __syncthreads();
    }
    float gm = sred[0];
    if (!isfinite(gm)) gm = 0.f;
    __syncthreads();

    float sm = 0.f;
    for (int i = beg + t; i < end; i += 256) sm += __expf(gate[i] - gm);
    sred[t] = sm;
    __syncthreads();
    for (int off = 128; off; off >>= 1) {
        if (t < off) sred[t] += sred[t + off];
        __syncthreads();
    }
    if (t == 0) {
        gm_out[g] = gm;
        inv_gden_out[g] = 1.f / (sred[0] + 1e-16f);
    }
}

__global__ void zero_kernel(float* __restrict__ p, int n) {
    int i = blockIdx.x * blockDim.x + threadIdx.x;
    if (i < n) p[i] = 0.f;
}

// ---------------- pooling, stage 2: weighted segment-sum over nodes ----------------
__global__ __launch_bounds__(384)
void pool_accum_kernel(const float* __restrict__ H2, const float* __restrict__ gate,
                       const int* __restrict__ batch, const float* __restrict__ gm,
                       const float* __restrict__ inv_gden, int n_nodes,
                       float* __restrict__ pooled) {
    const int NPB = 256;
    int t = threadIdx.x;
    int group = t / 96;
    int c = t - group * 96;
    if (group >= 4) return;
    int nbeg = blockIdx.x * NPB;
    int nend = min(nbeg + NPB, n_nodes);

    float acc = 0.f;
    int curg = -1;
    for (int i = nbeg + group; i < nend; i += 4) {
        int g = batch[i];
        if (g != curg) {
            if (curg >= 0) atomicAdd(&pooled[(size_t)curg * 96 + c], acc);
            acc = 0.f;
            curg = g;
        }
        float w = __expf(gate[i] - gm[curg]) * inv_gden[curg];
        acc = fmaf(w, H2[(size_t)i * 96 + c], acc);
    }
    if (curg >= 0) atomicAdd(&pooled[(size_t)curg * 96 + c], acc);
}

// ---------------- final MLP (one block per graph) ----------------
__global__ void final_kernel(const float* __restrict__ pooled, const float* __restrict__ f_w1,
                             const float* __restrict__ f_b1, const float* __restrict__ f_w2,
                             const float* __restrict__ f_b2, float* __restrict__ out) {
    int g = blockIdx.x, t = threadIdx.x;   // 96 threads
    __shared__ float sp[96], sh[96];
    sp[t] = pooled[(size_t)g * 96 + t];
    __syncthreads();
    float a = f_b1[t];
    for (int k = 0; k < 96; k++) a = fmaf(sp[k], f_w1[k * 96 + t], a);
    sh[t] = fmaxf(a, 0.f);
    __syncthreads();
    if (t < 3) {
        float o = f_b2[t];
        for (int k = 0; k < 96; k++) o = fmaf(sh[k], f_w2[k * 3 + t], o);
        out[g * 3 + t] = o;
    }
}

// ---------------- launch ----------------
extern "C" void kernel_launch(void* const* d_in, const int* in_sizes, int n_in,
                              void* d_out, int out_size, void* d_ws, size_t ws_size,
                              hipStream_t stream) {
    const float* x    = (const float*)d_in[0];
    const int*   ei   = (const int*)d_in[1];
    const int*   batch= (const int*)d_in[2];
    const float* W1   = (const float*)d_in[4];
    const float* as1  = (const float*)d_in[5];
    const float* ad1  = (const float*)d_in[6];
    const float* b1   = (const float*)d_in[7];
    const float* W2   = (const float*)d_in[8];
    const float* as2  = (const float*)d_in[9];
    const float* ad2  = (const float*)d_in[10];
    const float* b2   = (const float*)d_in[11];
    const float* g_w1 = (const float*)d_in[12];
    const float* g_b1 = (const float*)d_in[13];
    const float* g_w2 = (const float*)d_in[14];
    const float* g_b2 = (const float*)d_in[15];
    const float* f_w1 = (const float*)d_in[16];
    const float* f_b1 = (const float*)d_in[17];
    const float* f_w2 = (const float*)d_in[18];
    const float* f_b2 = (const float*)d_in[19];
    float* out = (float*)d_out;

    int N = in_sizes[0] / 128;
    int E = in_sizes[1] / 2;
    int G = out_size / 3;
    const int* srcv = ei;
    const int* dstv = ei + E;

    char* p = (char*)d_ws;
    auto alloc = [&](size_t bytes) {
        char* q = p;
        p += (bytes + 255) & ~(size_t)255;
        return q;
    };
    float* hA    = (float*)alloc((size_t)N * 96 * 4);
    float* hB    = (float*)alloc((size_t)N * 96 * 4);
    float* AS    = (float*)alloc((size_t)N * 4 * 4);
    float* AD    = (float*)alloc((size_t)N * 4 * 4);
    float* gatev = (float*)alloc((size_t)N * 4);
    float* pooled= (float*)alloc((size_t)G * 96 * 4);
    float* gmv   = (float*)alloc((size_t)G * 4);
    float* invgd = (float*)alloc((size_t)G * 4);
    int*   deg   = (int*)alloc((size_t)N * 4);
    int*   pos   = (int*)alloc((size_t)N * 4);
    int*   rowptr= (int*)alloc(((size_t)N + 1) * 4);
    int*   bsum  = (int*)alloc((size_t)256 * 4);
    int*   col   = (int*)alloc((size_t)(E + N) * 4);

    const int B = 256;
    int gemm_blocks = (N + 63) / 64;
    int nb_scan = (N + 1023) / 1024;

    // CSR build (by dst, self-loops included)
    init_deg_kernel<<<(N + B - 1) / B, B, 0, stream>>>(deg, N);
    hist_kernel<<<(E + B - 1) / B, B, 0, stream>>>(dstv, deg, E);
    scan_bsum_kernel<<<nb_scan, 256, 0, stream>>>(deg, bsum, N);
    scan_bsum_scan_kernel<<<1, 256, 0, stream>>>(bsum, nb_scan, rowptr, N);
    scan_local_kernel<<<nb_scan, 256, 0, stream>>>(deg, bsum, rowptr, pos, N);
    fill_self_kernel<<<(N + B - 1) / B, B, 0, stream>>>(pos, col, N);
    fill_edge_kernel<<<(E + B - 1) / B, B, 0, stream>>>(srcv, dstv, pos, col, E);

    // layer 1
    tiled_gemm_kernel<128, 96, 6, 0><<<gemm_blocks, 256, 0, stream>>>(
        x, W1, as1, ad1, nullptr, hA, AS, AD, N);
    gat_agg_wave_kernel<<<(N + 3) / 4, 256, 0, stream>>>(hA, AS, AD, rowptr, col, b1, hB, N);
    // layer 2
    tiled_gemm_kernel<96, 96, 6, 0><<<gemm_blocks, 256, 0, stream>>>(
        hB, W2, as2, ad2, nullptr, hA, AS, AD, N);
    gat_agg_wave_kernel<<<(N + 3) / 4, 256, 0, stream>>>(hA, AS, AD, rowptr, col, b2, hB, N);

    // pooling
    tiled_gemm_kernel<96, 48, 3, 1><<<gemm_blocks, 256, 0, stream>>>(
        hB, g_w1, g_b1, g_w2, g_b2, gatev, nullptr, nullptr, N);
    gate_stats_kernel<<<G, 256, 0, stream>>>(gatev, batch, N, gmv, invgd);
    zero_kernel<<<(G * 96 + B - 1) / B, B, 0, stream>>>(pooled, G * 96);
    pool_accum_kernel<<<(N + 255) / 256, 384, 0, stream>>>(
        hB, gatev, batch, gmv, invgd, N, pooled);
    final_kernel<<<G, 96, 0, stream>>>(pooled, f_w1, f_b1, f_w2, f_b2, out);
}

// Round 5
// 352.386 us; speedup vs baseline: 2.6614x; 1.0204x over previous
//
#include <hip/hip_runtime.h>
#include <cmath>

// ---------------- CSR build kernels ----------------

__global__ void init_deg_kernel(int* __restrict__ deg, int n) {
    int i = blockIdx.x * blockDim.x + threadIdx.x;
    if (i < n) deg[i] = 1;   // self-loop
}

__global__ void hist_kernel(const int* __restrict__ dst, int* __restrict__ deg, int E) {
    int e = blockIdx.x * blockDim.x + threadIdx.x;
    if (e < E) atomicAdd(&deg[dst[e]], 1);
}

// ---- hierarchical exclusive scan: deg[0..n) -> rowptr[0..n], pos copy ----
__global__ void scan_bsum_kernel(const int* __restrict__ deg, int* __restrict__ bsum, int n) {
    __shared__ int s[256];
    int t = threadIdx.x;
    int base = blockIdx.x * 1024;
    int sum = 0;
#pragma unroll
    for (int j = 0; j < 4; j++) {
        int i = base + j * 256 + t;
        if (i < n) sum += deg[i];
    }
    s[t] = sum;
    __syncthreads();
    for (int off = 128; off; off >>= 1) {
        if (t < off) s[t] += s[t + off];
        __syncthreads();
    }
    if (t == 0) bsum[blockIdx.x] = s[0];
}

__global__ void scan_bsum_scan_kernel(int* __restrict__ bsum, int nb,
                                      int* __restrict__ rowptr, int n) {
    __shared__ int s[256];
    int t = threadIdx.x;
    int v = (t < nb) ? bsum[t] : 0;
    s[t] = v;
    __syncthreads();
    for (int off = 1; off < 256; off <<= 1) {
        int x = (t >= off) ? s[t - off] : 0;
        __syncthreads();
        s[t] += x;
        __syncthreads();
    }
    if (t < nb) bsum[t] = s[t] - v;   // exclusive
    if (t == 255) rowptr[n] = s[255];
}

__global__ void scan_local_kernel(const int* __restrict__ deg, const int* __restrict__ bsum,
                                  int* __restrict__ rowptr, int* __restrict__ pos, int n) {
    __shared__ int s[256];
    int t = threadIdx.x;
    int base = blockIdx.x * 1024;
    int d[4];
    int sum = 0;
#pragma unroll
    for (int j = 0; j < 4; j++) {
        int i = base + t * 4 + j;
        d[j] = (i < n) ? deg[i] : 0;
        sum += d[j];
    }
    s[t] = sum;
    __syncthreads();
    for (int off = 1; off < 256; off <<= 1) {
        int x = (t >= off) ? s[t - off] : 0;
        __syncthreads();
        s[t] += x;
        __syncthreads();
    }
    int run = bsum[blockIdx.x] + s[t] - sum;
#pragma unroll
    for (int j = 0; j < 4; j++) {
        int i = base + t * 4 + j;
        if (i < n) { rowptr[i] = run; pos[i] = run; }
        run += d[j];
    }
}

// merged: edges then self-loops
__global__ void fill_kernel(const int* __restrict__ src, const int* __restrict__ dst,
                            int* __restrict__ pos, int* __restrict__ col, int E, int N) {
    int i = blockIdx.x * blockDim.x + threadIdx.x;
    if (i < E) {
        int p = atomicAdd(&pos[dst[i]], 1);
        col[p] = src[i];
    } else if (i < E + N) {
        int n = i - E;
        int p = atomicAdd(&pos[n], 1);
        col[p] = n;
    }
}

// ---------------- tiled f32 GEMM (BM=64, BK=16, 256 threads) ----------------
template<int K, int NCOL, int TN, int MODE>
__global__ __launch_bounds__(256)
void tiled_gemm_kernel(const float* __restrict__ X, const float* __restrict__ W,
                       const float* __restrict__ v1, const float* __restrict__ v2,
                       const float* __restrict__ v3,
                       float* __restrict__ H, float* __restrict__ AS, float* __restrict__ AD,
                       int n_nodes) {
    const int t = threadIdx.x;
    const int tx = t & 15, ty = t >> 4;
    const int c0 = tx * TN;
    const int m0 = ty * 4;
    const int node0 = blockIdx.x * 64;

    __shared__ float As[16][68];
    __shared__ float Bs[16][NCOL];

    float acc[4][TN];
#pragma unroll
    for (int i = 0; i < 4; i++)
#pragma unroll
        for (int j = 0; j < TN; j++) acc[i][j] = 0.f;

    const int am = t >> 2, akq = t & 3;

    for (int kb = 0; kb < K; kb += 16) {
        float4 av = make_float4(0.f, 0.f, 0.f, 0.f);
        int anode = node0 + am;
        if (anode < n_nodes)
            av = *reinterpret_cast<const float4*>(X + (size_t)anode * K + kb + akq * 4);
        As[akq * 4 + 0][am] = av.x;
        As[akq * 4 + 1][am] = av.y;
        As[akq * 4 + 2][am] = av.z;
        As[akq * 4 + 3][am] = av.w;
        {
            const float4* wsrc = reinterpret_cast<const float4*>(W + (size_t)kb * NCOL);
            float4* bdst = reinterpret_cast<float4*>(&Bs[0][0]);
            for (int i = t; i < 16 * NCOL / 4; i += 256) bdst[i] = wsrc[i];
        }
        __syncthreads();
#pragma unroll
        for (int k = 0; k < 16; k++) {
            float4 a4 = *reinterpret_cast<const float4*>(&As[k][m0]);
            float a[4] = {a4.x, a4.y, a4.z, a4.w};
            float b[TN];
            if constexpr ((TN & 1) == 0) {
#pragma unroll
                for (int j = 0; j < TN / 2; j++) {
                    float2 b2 = *reinterpret_cast<const float2*>(&Bs[k][c0 + 2 * j]);
                    b[2 * j] = b2.x; b[2 * j + 1] = b2.y;
                }
            } else {
#pragma unroll
                for (int j = 0; j < TN; j++) b[j] = Bs[k][c0 + j];
            }
#pragma unroll
            for (int i = 0; i < 4; i++)
#pragma unroll
                for (int j = 0; j < TN; j++)
                    acc[i][j] = fmaf(a[i], b[j], acc[i][j]);
        }
        __syncthreads();
    }

    if constexpr (MODE == 0) {
        __shared__ float s_as[64][16];
        __shared__ float s_ad[64][16];
#pragma unroll
        for (int i = 0; i < 4; i++) {
            int node = node0 + m0 + i;
            float asp = 0.f, adp = 0.f;
#pragma unroll
            for (int j = 0; j < TN; j++) {
                asp = fmaf(acc[i][j], v1[c0 + j], asp);
                adp = fmaf(acc[i][j], v2[c0 + j], adp);
            }
            s_as[m0 + i][tx] = asp;
            s_ad[m0 + i][tx] = adp;
            if (node < n_nodes) {
#pragma unroll
                for (int j = 0; j < TN / 2; j++) {
                    float2 o;
                    o.x = acc[i][2 * j]; o.y = acc[i][2 * j + 1];
                    *reinterpret_cast<float2*>(H + (size_t)node * NCOL + c0 + 2 * j) = o;
                }
            }
        }
        __syncthreads();
        int m = t >> 2, head = t & 3;
        int node = node0 + m;
        if (node < n_nodes) {
            float s1 = s_as[m][head * 4 + 0] + s_as[m][head * 4 + 1]
                     + s_as[m][head * 4 + 2] + s_as[m][head * 4 + 3];
            float s2 = s_ad[m][head * 4 + 0] + s_ad[m][head * 4 + 1]
                     + s_ad[m][head * 4 + 2] + s_ad[m][head * 4 + 3];
            AS[(size_t)node * 4 + head] = s1;
            AD[(size_t)node * 4 + head] = s2;
        }
    } else {
        __shared__ float s_g[64][16];
#pragma unroll
        for (int i = 0; i < 4; i++) {
            float p = 0.f;
#pragma unroll
            for (int j = 0; j < TN; j++) {
                float a = acc[i][j] + v1[c0 + j];
                a = fmaxf(a, 0.f);
                p = fmaf(a, v2[c0 + j], p);
            }
            s_g[m0 + i][tx] = p;
        }
        __syncthreads();
        if (t < 64) {
            int node = node0 + t;
            if (node < n_nodes) {
                float s = 0.f;
#pragma unroll
                for (int j = 0; j < 16; j++) s += s_g[t][j];
                H[node] = s + v3[0];
            }
        }
    }
}

// ---------------- GAT aggregation: wave-synchronous, MLP-unrolled ----------------
// 1 wave per node, 4 waves/block. Per 16-edge chunk: hoist all 16 (src,weight)
// broadcasts into registers (static indices), then gather in unrolled groups
// of 4 with 4 independent accumulators -> many loads in flight.
__global__ __launch_bounds__(256)
void gat_agg_wave_kernel(const float* __restrict__ H, const float* __restrict__ AS,
                         const float* __restrict__ AD, const int* __restrict__ rowptr,
                         const int* __restrict__ col, const float* __restrict__ bias,
                         float* __restrict__ OUT, int n_nodes) {
    int wid = threadIdx.x >> 6;
    int lane = threadIdx.x & 63;
    int n = blockIdx.x * 4 + wid;
    if (n >= n_nodes) return;   // wave-uniform exit
    int beg = rowptr[n];
    int deg = rowptr[n + 1] - beg;

    int h = lane & 3;
    int slot = lane >> 2;
    float ad_n = AD[(size_t)n * 4 + h];

    // Phase A: per-head max of leaky_relu(as[src]+ad[n])
    float mymax = -INFINITY;
    for (int i = slot; i < deg; i += 16) {
        int s = col[beg + i];
        float v = AS[(size_t)s * 4 + h] + ad_n;
        v = v > 0.f ? v : 0.2f * v;
        mymax = fmaxf(mymax, v);
    }
#pragma unroll
    for (int m = 4; m <= 32; m <<= 1)
        mymax = fmaxf(mymax, __shfl_xor(mymax, m, 64));
    float m_h = mymax;

    int c = lane;                       // float2 channel-pair index
    bool cown = c < 48;
    int head_c = cown ? (c / 12) : 0;   // head of channels (2c,2c+1)
    const float2* __restrict__ Hc = reinterpret_cast<const float2*>(H) + c;

    float denom_part = 0.f;
    float2 acc0 = make_float2(0.f, 0.f), acc1 = make_float2(0.f, 0.f);
    float2 acc2 = make_float2(0.f, 0.f), acc3 = make_float2(0.f, 0.f);

    for (int base = 0; base < deg; base += 16) {
        int ce = base + slot;
        int s_e = 0;
        float ex = 0.f;
        if (ce < deg) {
            s_e = col[beg + ce];
            float v = AS[(size_t)s_e * 4 + h] + ad_n;
            v = v > 0.f ? v : 0.2f * v;
            ex = __expf(v - m_h);
        }
        denom_part += ex;
        int cnt = min(16, deg - base);

        // hoist all 16 broadcasts into registers (static indices)
        int sbv[16];
        float wv[16];
#pragma unroll
        for (int i = 0; i < 16; i++) {
            sbv[i] = __shfl(s_e, i * 4, 64);
            wv[i]  = __shfl(ex,  i * 4 + head_c, 64);
        }

#pragma unroll
        for (int g = 0; g < 16; g += 4) {
            if (g < cnt && cown) {
                // 4 independent loads (padded slots: weight 0, row 0)
                float2 v0 = Hc[(size_t)sbv[g + 0] * 48];
                float2 v1 = Hc[(size_t)sbv[g + 1] * 48];
                float2 v2 = Hc[(size_t)sbv[g + 2] * 48];
                float2 v3 = Hc[(size_t)sbv[g + 3] * 48];
                acc0.x = fmaf(v0.x, wv[g + 0], acc0.x);
                acc0.y = fmaf(v0.y, wv[g + 0], acc0.y);
                acc1.x = fmaf(v1.x, wv[g + 1], acc1.x);
                acc1.y = fmaf(v1.y, wv[g + 1], acc1.y);
                acc2.x = fmaf(v2.x, wv[g + 2], acc2.x);
                acc2.y = fmaf(v2.y, wv[g + 2], acc2.y);
                acc3.x = fmaf(v3.x, wv[g + 3], acc3.x);
                acc3.y = fmaf(v3.y, wv[g + 3], acc3.y);
            }
        }
    }

#pragma unroll
    for (int m = 4; m <= 32; m <<= 1)
        denom_part += __shfl_xor(denom_part, m, 64);
    float den = __shfl(denom_part, head_c, 64);

    if (cown) {
        float2 acc;
        acc.x = (acc0.x + acc1.x) + (acc2.x + acc3.x);
        acc.y = (acc0.y + acc1.y) + (acc2.y + acc3.y);
        float2 b2 = reinterpret_cast<const float2*>(bias)[c];
        float inv = 1.f / (den + 1e-16f);
        float ox = acc.x * inv + b2.x;
        float oy = acc.y * inv + b2.y;
        ox = ox > 0.f ? ox : (__expf(ox) - 1.f);   // ELU
        oy = oy > 0.f ? oy : (__expf(oy) - 1.f);
        reinterpret_cast<float2*>(OUT)[(size_t)n * 48 + c] = make_float2(ox, oy);
    }
}

// ---------------- pooling, stage 1: per-graph softmax stats (+pooled zeroing) ----------------
__device__ __forceinline__ int lower_bound_dev(const int* __restrict__ arr, int n, int key) {
    int lo = 0, hi = n;
    while (lo < hi) {
        int mid = (lo + hi) >> 1;
        if (arr[mid] < key) lo = mid + 1; else hi = mid;
    }
    return lo;
}

__global__ void gate_stats_kernel(const float* __restrict__ gate, const int* __restrict__ batch,
                                  int n_nodes, float* __restrict__ gm_out,
                                  float* __restrict__ inv_gden_out, float* __restrict__ pooled) {
    int g = blockIdx.x, t = threadIdx.x;   // 256 threads
    if (t < 96) pooled[(size_t)g * 96 + t] = 0.f;
    __shared__ int sb, se;
    __shared__ float sred[256];
    if (t == 0) {
        sb = lower_bound_dev(batch, n_nodes, g);
        se = lower_bound_dev(batch, n_nodes, g + 1);
    }
    __syncthreads();
    int beg = sb, end = se;

    float mx = -INFINITY;
    for (int i = beg + t; i < end; i += 256) mx = fmaxf(mx, gate[i]);
    sred[t] = mx;
    __syncthreads();
    for (int off = 128; off; off >>= 1) {
        if (t < off) sred[t] = fmaxf(sred[t], sred[t + off]);
        __syncthreads();
    }
    float gm = sred[0];
    if (!isfinite(gm)) gm = 0.f;
    __syncthreads();

    float sm = 0.f;
    for (int i = beg + t; i < end; i += 256) sm += __expf(gate[i] - gm);
    sred[t] = sm;
    __syncthreads();
    for (int off = 128; off; off >>= 1) {
        if (t < off) sred[t] += sred[t + off];
        __syncthreads();
    }
    if (t == 0) {
        gm_out[g] = gm;
        inv_gden_out[g] = 1.f / (sred[0] + 1e-16f);
    }
}

// ---------------- pooling, stage 2: weighted segment-sum over nodes ----------------
__global__ __launch_bounds__(384)
void pool_accum_kernel(const float* __restrict__ H2, const float* __restrict__ gate,
                       const int* __restrict__ batch, const float* __restrict__ gm,
                       const float* __restrict__ inv_gden, int n_nodes,
                       float* __restrict__ pooled) {
    const int NPB = 256;
    int t = threadIdx.x;
    int group = t / 96;
    int c = t - group * 96;
    if (group >= 4) return;
    int nbeg = blockIdx.x * NPB;
    int nend = min(nbeg + NPB, n_nodes);

    float acc = 0.f;
    int curg = -1;
    for (int i = nbeg + group; i < nend; i += 4) {
        int g = batch[i];
        if (g != curg) {
            if (curg >= 0) atomicAdd(&pooled[(size_t)curg * 96 + c], acc);
            acc = 0.f;
            curg = g;
        }
        float w = __expf(gate[i] - gm[curg]) * inv_gden[curg];
        acc = fmaf(w, H2[(size_t)i * 96 + c], acc);
    }
    if (curg >= 0) atomicAdd(&pooled[(size_t)curg * 96 + c], acc);
}

// ---------------- final MLP (one block per graph) ----------------
__global__ void final_kernel(const float* __restrict__ pooled, const float* __restrict__ f_w1,
                             const float* __restrict__ f_b1, const float* __restrict__ f_w2,
                             const float* __restrict__ f_b2, float* __restrict__ out) {
    int g = blockIdx.x, t = threadIdx.x;   // 96 threads
    __shared__ float sp[96], sh[96];
    sp[t] = pooled[(size_t)g * 96 + t];
    __syncthreads();
    float a = f_b1[t];
    for (int k = 0; k < 96; k++) a = fmaf(sp[k], f_w1[k * 96 + t], a);
    sh[t] = fmaxf(a, 0.f);
    __syncthreads();
    if (t < 3) {
        float o = f_b2[t];
        for (int k = 0; k < 96; k++) o = fmaf(sh[k], f_w2[k * 3 + t], o);
        out[g * 3 + t] = o;
    }
}

// ---------------- launch ----------------
extern "C" void kernel_launch(void* const* d_in, const int* in_sizes, int n_in,
                              void* d_out, int out_size, void* d_ws, size_t ws_size,
                              hipStream_t stream) {
    const float* x    = (const float*)d_in[0];
    const int*   ei   = (const int*)d_in[1];
    const int*   batch= (const int*)d_in[2];
    const float* W1   = (const float*)d_in[4];
    const float* as1  = (const float*)d_in[5];
    const float* ad1  = (const float*)d_in[6];
    const float* b1   = (const float*)d_in[7];
    const float* W2   = (const float*)d_in[8];
    const float* as2  = (const float*)d_in[9];
    const float* ad2  = (const float*)d_in[10];
    const float* b2   = (const float*)d_in[11];
    const float* g_w1 = (const float*)d_in[12];
    const float* g_b1 = (const float*)d_in[13];
    const float* g_w2 = (const float*)d_in[14];
    const float* g_b2 = (const float*)d_in[15];
    const float* f_w1 = (const float*)d_in[16];
    const float* f_b1 = (const float*)d_in[17];
    const float* f_w2 = (const float*)d_in[18];
    const float* f_b2 = (const float*)d_in[19];
    float* out = (float*)d_out;

    int N = in_sizes[0] / 128;
    int E = in_sizes[1] / 2;
    int G = out_size / 3;
    const int* srcv = ei;
    const int* dstv = ei + E;

    char* p = (char*)d_ws;
    auto alloc = [&](size_t bytes) {
        char* q = p;
        p += (bytes + 255) & ~(size_t)255;
        return q;
    };
    float* hA    = (float*)alloc((size_t)N * 96 * 4);
    float* hB    = (float*)alloc((size_t)N * 96 * 4);
    float* AS    = (float*)alloc((size_t)N * 4 * 4);
    float* AD    = (float*)alloc((size_t)N * 4 * 4);
    float* gatev = (float*)alloc((size_t)N * 4);
    float* pooled= (float*)alloc((size_t)G * 96 * 4);
    float* gmv   = (float*)alloc((size_t)G * 4);
    float* invgd = (float*)alloc((size_t)G * 4);
    int*   deg   = (int*)alloc((size_t)N * 4);
    int*   pos   = (int*)alloc((size_t)N * 4);
    int*   rowptr= (int*)alloc(((size_t)N + 1) * 4);
    int*   bsum  = (int*)alloc((size_t)256 * 4);
    int*   col   = (int*)alloc((size_t)(E + N) * 4);

    const int B = 256;
    int gemm_blocks = (N + 63) / 64;
    int nb_scan = (N + 1023) / 1024;

    // CSR build (by dst, self-loops included)
    init_deg_kernel<<<(N + B - 1) / B, B, 0, stream>>>(deg, N);
    hist_kernel<<<(E + B - 1) / B, B, 0, stream>>>(dstv, deg, E);
    scan_bsum_kernel<<<nb_scan, 256, 0, stream>>>(deg, bsum, N);
    scan_bsum_scan_kernel<<<1, 256, 0, stream>>>(bsum, nb_scan, rowptr, N);
    scan_local_kernel<<<nb_scan, 256, 0, stream>>>(deg, bsum, rowptr, pos, N);
    fill_kernel<<<(E + N + B - 1) / B, B, 0, stream>>>(srcv, dstv, pos, col, E, N);

    // layer 1
    tiled_gemm_kernel<128, 96, 6, 0><<<gemm_blocks, 256, 0, stream>>>(
        x, W1, as1, ad1, nullptr, hA, AS, AD, N);
    gat_agg_wave_kernel<<<(N + 3) / 4, 256, 0, stream>>>(hA, AS, AD, rowptr, col, b1, hB, N);
    // layer 2
    tiled_gemm_kernel<96, 96, 6, 0><<<gemm_blocks, 256, 0, stream>>>(
        hB, W2, as2, ad2, nullptr, hA, AS, AD, N);
    gat_agg_wave_kernel<<<(N + 3) / 4, 256, 0, stream>>>(hA, AS, AD, rowptr, col, b2, hB, N);

    // pooling
    tiled_gemm_kernel<96, 48, 3, 1><<<gemm_blocks, 256, 0, stream>>>(
        hB, g_w1, g_b1, g_w2, g_b2, gatev, nullptr, nullptr, N);
    gate_stats_kernel<<<G, 256, 0, stream>>>(gatev, batch, N, gmv, invgd, pooled);
    pool_accum_kernel<<<(N + 255) / 256, 384, 0, stream>>>(
        hB, gatev, batch, gmv, invgd, N, pooled);
    final_kernel<<<G, 96, 0, stream>>>(pooled, f_w1, f_b1, f_w2, f_b2, out);
}